// Round 6
// baseline (170.685 us; speedup 1.0000x reference)
//
#include <hip/hip_runtime.h>
#include <hip/hip_bf16.h>
#include <cstdint>

#define HASH_SIZE (1u<<19)
#define NPTS 262144
#define DENS_N 2097152

typedef unsigned short u16;
typedef u16 u16x8 __attribute__((ext_vector_type(8)));
typedef __bf16 bf16x8 __attribute__((ext_vector_type(8)));
typedef float f32x4 __attribute__((ext_vector_type(4)));

__device__ __forceinline__ u16 f2bf(float f){
  uint32_t u = __builtin_bit_cast(uint32_t, f);
  u += 0x7fffu + ((u>>16)&1u);       // RNE; inputs are finite
  return (u16)(u>>16);
}
__device__ __forceinline__ float bf2f(u16 s){
  uint32_t u = ((uint32_t)s)<<16;
  return __builtin_bit_cast(float, u);
}

// W1 [512][64] f32 -> W1T [64][512] bf16 ; W2 [64][64] f32 -> W2T [64][64] bf16
__global__ void prep_weights(const float* __restrict__ W1, const float* __restrict__ W2,
                             u16* __restrict__ W1T, u16* __restrict__ W2T){
  int t = blockIdx.x*blockDim.x + threadIdx.x;
  int stride = gridDim.x*blockDim.x;
  for (int i=t; i<64*512; i+=stride){ int o=i>>9, k=i&511; W1T[i] = f2bf(W1[k*64+o]); }
  for (int i=t; i<64*64;  i+=stride){ int o=i>>6, k=i&63;  W2T[i] = f2bf(W2[k*64+o]); }
}

__global__ void density_sigmoid(const float4* __restrict__ in, float4* __restrict__ out){
  int i = blockIdx.x*blockDim.x + threadIdx.x;   // exactly 524288 threads
  float4 v = in[i];
  v.x = 1.f/(1.f+__expf(-v.x));
  v.y = 1.f/(1.f+__expf(-v.y));
  v.z = 1.f/(1.f+__expf(-v.z));
  v.w = 1.f/(1.f+__expf(-v.w));
  out[i] = v;
}

// PERSISTENT: 256 blocks (1/CU), 512 threads = 8 waves. Each block stages
// W1/W2 into LDS ONCE, then loops over 8 batches of 128 points with a 2-deep
// half-batch (8-level) software pipeline: batch b+1's gathers are in flight
// while batch b's MFMAs drain, so the gather pipe never idles.
__global__ void __launch_bounds__(512) fused_mlp(
    const float* __restrict__ xyz, const float* __restrict__ fg,
    const u16* __restrict__ W1T, const u16* __restrict__ W2T,
    const float* __restrict__ b1, const float* __restrict__ b2,
    const float* __restrict__ W3, const float* __restrict__ b3,
    float* __restrict__ color)
{
  __shared__ u16 w1s[64*512];      // 64 KiB, granule-swizzled
  __shared__ u16 w2s[64*64];       // 8 KiB, granule-swizzled
  __shared__ u16 hbuf[8][16*64];   // 16 KiB; h1 then h2 in place (same-wave)

  const int t = threadIdx.x;
  const int wave = t >> 6;
  const int lane = t & 63;
  const int p  = lane & 15;            // point within this wave's 16-point tile
  const int kg = lane >> 4;            // k-subgroup 0..3
  const int base = (blockIdx.x << 10) + (wave << 4) + p;  // batch 0 point id

  // issue 8 levels [s0, s0+8) of gathers for point (xx,yy,zz)
  auto issue8 = [&](float xx, float yy, float zz, int s0, float4* f0, float4* f1){
    #pragma unroll
    for (int j=0; j<8; ++j){
      const int s = s0 + j;
      const float resf = (float)(16 << s);
      uint32_t ix = (uint32_t)(xx*resf);
      uint32_t iy = (uint32_t)(yy*resf);
      uint32_t iz = (uint32_t)(zz*resf);
      uint32_t h = (ix ^ (iy*2654435761u) ^ (iz*805459861u)) & (HASH_SIZE-1u);
      const float* ap = fg + (size_t)((((uint32_t)s<<19) | h) * 32u) + (kg<<3);
      f0[j] = *(const float4*)ap;
      f1[j] = *(const float4*)(ap+4);
    }
  };
  // drain 8 levels: convert + 32 MFMA against w1s
  auto drain8 = [&](int s0, const float4* f0, const float4* f1, f32x4* acc){
    #pragma unroll
    for (int j=0; j<8; ++j){
      const int s = s0 + j;
      bf16x8 ab = { (__bf16)f0[j].x, (__bf16)f0[j].y, (__bf16)f0[j].z, (__bf16)f0[j].w,
                    (__bf16)f1[j].x, (__bf16)f1[j].y, (__bf16)f1[j].z, (__bf16)f1[j].w };
      #pragma unroll
      for (int tt=0; tt<4; ++tt){
        const int col = (lane&15) + (tt<<4);
        u16x8 bu = *(const u16x8*)(w1s + (col<<9) + ((((s<<2)+kg) ^ (col&7))<<3));
        acc[tt] = __builtin_amdgcn_mfma_f32_16x16x32_bf16(
            ab, __builtin_bit_cast(bf16x8, bu), acc[tt], 0,0,0);
      }
    }
  };

  // ---- prologue: batch 0 gathers in flight before anything else ----
  float4 fa0[8], fa1[8], fb0[8], fb1[8];
  {
    const float x = xyz[base*3+0], y = xyz[base*3+1], z = xyz[base*3+2];
    issue8(x, y, z, 0, fa0, fa1);
    issue8(x, y, z, 8, fb0, fb1);
  }
  __builtin_amdgcn_sched_barrier(0);

  // ---- stage W1T/W2T into LDS once (cooperative, swizzled 16B granules) ----
  #pragma unroll
  for (int i=0; i<8; ++i){
    int g = t + (i<<9);                 // 512 threads x 8 = 4096 granules
    int col = g >> 6, gr = g & 63;
    u16x8 v = *(const u16x8*)(W1T + (g<<3));
    *(u16x8*)(w1s + (col<<9) + ((gr ^ (col&7))<<3)) = v;
  }
  {
    int g = t;                           // 512 granules
    int col = g >> 3, gr = g & 7;
    u16x8 v = *(const u16x8*)(W2T + (g<<3));
    *(u16x8*)(w2s + (col<<6) + ((gr ^ (col&7))<<3)) = v;
  }
  // per-thread biases (col fixed per thread) — hoisted out of the batch loop
  float bias1[4], bias2[4];
  #pragma unroll
  for (int tt=0; tt<4; ++tt){
    bias1[tt] = b1[(lane&15) + (tt<<4)];
    bias2[tt] = b2[(lane&15) + (tt<<4)];
  }
  __syncthreads();

  // ---- main loop: 8 batches, 2-deep half-batch pipeline ----
  #pragma unroll 1
  for (int b=0; b<8; ++b){
    // prefetch next batch coords early (latency hidden under drains)
    float xn=0.f, yn=0.f, zn=0.f;
    if (b < 7){
      const int gpn = base + ((b+1)<<7);
      xn = xyz[gpn*3+0]; yn = xyz[gpn*3+1]; zn = xyz[gpn*3+2];
    }

    f32x4 acc[4];
    #pragma unroll
    for (int tt=0; tt<4; ++tt) acc[tt] = (f32x4){0.f,0.f,0.f,0.f};

    // drain H0(b), then refill fa with H0(b+1)
    drain8(0, fa0, fa1, acc);
    __builtin_amdgcn_sched_barrier(0);
    if (b < 7) issue8(xn, yn, zn, 0, fa0, fa1);
    __builtin_amdgcn_sched_barrier(0);
    // drain H1(b), then refill fb with H1(b+1)
    drain8(8, fb0, fb1, acc);
    __builtin_amdgcn_sched_barrier(0);
    if (b < 7) issue8(xn, yn, zn, 8, fb0, fb1);
    __builtin_amdgcn_sched_barrier(0);

    // ---- h1 = relu(acc + b1) -> hbuf (XOR-swizzled) ----
    #pragma unroll
    for (int tt=0; tt<4; ++tt){
      const int col = (lane&15) + (tt<<4);
      #pragma unroll
      for (int r=0; r<4; ++r){
        const int row = (kg<<2) + r;
        float v = acc[tt][r] + bias1[tt];
        v = v > 0.f ? v : 0.f;
        hbuf[wave][(row*64 + col) ^ ((row&7)<<3)] = f2bf(v);
      }
    }

    // ---- GEMM2: h1 @ W2 (same-wave LDS deps; no barrier) ----
    f32x4 acc2[4];
    #pragma unroll
    for (int tt=0; tt<4; ++tt) acc2[tt] = (f32x4){0.f,0.f,0.f,0.f};
    #pragma unroll
    for (int kc=0; kc<2; ++kc){
      const int aidx = (p*64 + kc*32 + kg*8) ^ ((p&7)<<3);
      u16x8 au = *(const u16x8*)(&hbuf[wave][aidx]);
      bf16x8 ab = __builtin_bit_cast(bf16x8, au);
      #pragma unroll
      for (int tt=0; tt<4; ++tt){
        const int col = (lane&15) + (tt<<4);
        u16x8 bu = *(const u16x8*)(w2s + (col<<6) + ((((kc<<2)+kg) ^ (col&7))<<3));
        acc2[tt] = __builtin_amdgcn_mfma_f32_16x16x32_bf16(
            ab, __builtin_bit_cast(bf16x8, bu), acc2[tt], 0,0,0);
      }
    }
    // overwrite h1 with h2 in place (all h1 reads precede; same-wave in-order)
    #pragma unroll
    for (int tt=0; tt<4; ++tt){
      const int col = (lane&15) + (tt<<4);
      #pragma unroll
      for (int r=0; r<4; ++r){
        const int row = (kg<<2) + r;
        float v = acc2[tt][r] + bias2[tt];
        v = v > 0.f ? v : 0.f;
        hbuf[wave][(row*64 + col) ^ ((row&7)<<3)] = f2bf(v);
      }
    }

    // ---- layer 3: [16 x 64] @ [64 x 3] + sigmoid ----
    if (lane < 48){
      const int pp = lane / 3, c = lane % 3;
      float sum = b3[c];
      #pragma unroll
      for (int o=0; o<64; ++o){
        sum += bf2f(hbuf[wave][(pp*64+o) ^ ((pp&7)<<3)]) * W3[o*3+c];
      }
      const int gpp = (blockIdx.x << 10) + (b<<7) + (wave << 4) + pp;
      color[(size_t)gpp*3 + c] = 1.f/(1.f+__expf(-sum));
    }
  }
}

extern "C" void kernel_launch(void* const* d_in, const int* in_sizes, int n_in,
                              void* d_out, int out_size, void* d_ws, size_t ws_size,
                              hipStream_t stream){
  const float* xyz  = (const float*)d_in[0];
  const float* fg   = (const float*)d_in[1];
  const float* dens = (const float*)d_in[2];
  const float* W1   = (const float*)d_in[3];
  const float* b1   = (const float*)d_in[4];
  const float* W2   = (const float*)d_in[5];
  const float* b2   = (const float*)d_in[6];
  const float* W3   = (const float*)d_in[7];
  const float* b3   = (const float*)d_in[8];
  float* out = (float*)d_out;

  u16* W1T = (u16*)d_ws;            // 64*512*2 = 64 KiB
  u16* W2T = W1T + 64*512;          // 64*64*2  =  8 KiB

  hipLaunchKernelGGL(prep_weights, dim3(64), dim3(256), 0, stream, W1, W2, W1T, W2T);
  hipLaunchKernelGGL(density_sigmoid, dim3(DENS_N/1024), dim3(256), 0, stream,
                     (const float4*)dens, (float4*)out);
  hipLaunchKernelGGL(fused_mlp, dim3(256), dim3(512), 0, stream,
                     xyz, fg, W1T, W2T, b1, b2, W3, b3, out + DENS_N);
}

// Round 7
// 155.070 us; speedup vs baseline: 1.1007x; 1.1007x over previous
//
#include <hip/hip_runtime.h>
#include <hip/hip_bf16.h>
#include <cstdint>

#define HASH_SIZE (1u<<19)
#define NPTS 262144
#define DENS_N 2097152

typedef unsigned short u16;
typedef u16 u16x8 __attribute__((ext_vector_type(8)));
typedef __bf16 bf16x8 __attribute__((ext_vector_type(8)));
typedef float f32x4 __attribute__((ext_vector_type(4)));

__device__ __forceinline__ u16 f2bf(float f){
  uint32_t u = __builtin_bit_cast(uint32_t, f);
  u += 0x7fffu + ((u>>16)&1u);       // RNE; inputs are finite
  return (u16)(u>>16);
}
__device__ __forceinline__ float bf2f(u16 s){
  uint32_t u = ((uint32_t)s)<<16;
  return __builtin_bit_cast(float, u);
}

// W1 [512][64] f32 -> W1T [64][512] bf16 ; W2 [64][64] f32 -> W2T [64][64] bf16
__global__ void prep_weights(const float* __restrict__ W1, const float* __restrict__ W2,
                             u16* __restrict__ W1T, u16* __restrict__ W2T){
  int t = blockIdx.x*blockDim.x + threadIdx.x;
  int stride = gridDim.x*blockDim.x;
  for (int i=t; i<64*512; i+=stride){ int o=i>>9, k=i&511; W1T[i] = f2bf(W1[k*64+o]); }
  for (int i=t; i<64*64;  i+=stride){ int o=i>>6, k=i&63;  W2T[i] = f2bf(W2[k*64+o]); }
}

__global__ void density_sigmoid(const float4* __restrict__ in, float4* __restrict__ out){
  int i = blockIdx.x*blockDim.x + threadIdx.x;   // exactly 524288 threads
  float4 v = in[i];
  v.x = 1.f/(1.f+__expf(-v.x));
  v.y = 1.f/(1.f+__expf(-v.y));
  v.z = 1.f/(1.f+__expf(-v.z));
  v.w = 1.f/(1.f+__expf(-v.w));
  out[i] = v;
}

// 512 threads = 8 independent waves, 16 points each (128 pts/block).
// W1T+W2T staged in LDS; only global VMEM in the hot path is the 32 gather
// loads per wave, marked NONTEMPORAL (no L1/L2 allocate — the gather stream
// has zero cache reuse; stop thrashing L2 with use-once lines).
__global__ void __launch_bounds__(512) fused_mlp(
    const float* __restrict__ xyz, const float* __restrict__ fg,
    const u16* __restrict__ W1T, const u16* __restrict__ W2T,
    const float* __restrict__ b1, const float* __restrict__ b2,
    const float* __restrict__ W3, const float* __restrict__ b3,
    float* __restrict__ color)
{
  __shared__ u16 w1s[64*512];      // 64 KiB, granule-swizzled
  __shared__ u16 w2s[64*64];       // 8 KiB, granule-swizzled
  __shared__ u16 hbuf[8][16*64];   // 16 KiB; h1 then h2 in place (same-wave)

  const int t = threadIdx.x;
  const int wave = t >> 6;
  const int lane = t & 63;
  const int p  = lane & 15;            // point within this wave's 16-point tile
  const int kg = lane >> 4;            // k-subgroup 0..3
  const int gp = (blockIdx.x << 7) + (wave << 4) + p;   // global point id

  // ---- issue gather loads FIRST (misses start early; 32 in flight/wave) ----
  const float x = xyz[gp*3+0];
  const float y = xyz[gp*3+1];
  const float z = xyz[gp*3+2];
  f32x4 a0[16], a1[16];
  #pragma unroll
  for (int s=0; s<16; ++s){
    const float resf = (float)(16 << s);
    uint32_t ix = (uint32_t)(x*resf);
    uint32_t iy = (uint32_t)(y*resf);
    uint32_t iz = (uint32_t)(z*resf);
    uint32_t h = (ix ^ (iy*2654435761u) ^ (iz*805459861u)) & (HASH_SIZE-1u);
    const f32x4* ap = (const f32x4*)(fg + (size_t)((((uint32_t)s<<19) | h) * 32u) + (kg<<3));
    a0[s] = __builtin_nontemporal_load(ap);
    a1[s] = __builtin_nontemporal_load(ap+1);
  }

  // ---- stage W1T/W2T into LDS (cooperative, swizzled granules of 16 B) ----
  // w1s: granule (col, g) g=0..63 stored at col*512 + (g ^ (col&7))*8 (u16 units)
  #pragma unroll
  for (int i=0; i<8; ++i){
    int g = t + (i<<9);                 // 512 threads x 8 = 4096 granules
    int col = g >> 6, gr = g & 63;
    u16x8 v = *(const u16x8*)(W1T + (g<<3));
    *(u16x8*)(w1s + (col<<9) + (((gr) ^ (col&7))<<3)) = v;
  }
  {
    int g = t;                           // 512 granules
    int col = g >> 3, gr = g & 7;
    u16x8 v = *(const u16x8*)(W2T + (g<<3));
    *(u16x8*)(w2s + (col<<6) + (((gr) ^ (col&7))<<3)) = v;
  }
  __syncthreads();

  // ---- GEMM1: features @ W1 -> h1 [16 x 64] ----
  f32x4 acc[4];
  #pragma unroll
  for (int tt=0; tt<4; ++tt) acc[tt] = (f32x4){0.f,0.f,0.f,0.f};

  #pragma unroll
  for (int s=0; s<16; ++s){
    bf16x8 ab = { (__bf16)a0[s][0], (__bf16)a0[s][1], (__bf16)a0[s][2], (__bf16)a0[s][3],
                  (__bf16)a1[s][0], (__bf16)a1[s][1], (__bf16)a1[s][2], (__bf16)a1[s][3] };
    #pragma unroll
    for (int tt=0; tt<4; ++tt){
      const int col = (lane&15) + (tt<<4);
      u16x8 bu = *(const u16x8*)(w1s + (col<<9) + ((((s<<2)+kg) ^ (col&7))<<3));
      acc[tt] = __builtin_amdgcn_mfma_f32_16x16x32_bf16(
          ab, __builtin_bit_cast(bf16x8, bu), acc[tt], 0,0,0);
    }
  }
  #pragma unroll
  for (int tt=0; tt<4; ++tt){
    const int col = (lane&15) + (tt<<4);
    const float bias = b1[col];
    #pragma unroll
    for (int r=0; r<4; ++r){
      const int row = (kg<<2) + r;        // C row = point within tile
      float v = acc[tt][r] + bias;
      v = v > 0.f ? v : 0.f;
      hbuf[wave][(row*64 + col) ^ ((row&7)<<3)] = f2bf(v);  // XOR-swizzled
    }
  }

  // ---- GEMM2: h1 @ W2 -> h2 [16 x 64] ---- (same-wave LDS deps; no barrier)
  f32x4 acc2[4];
  #pragma unroll
  for (int tt=0; tt<4; ++tt) acc2[tt] = (f32x4){0.f,0.f,0.f,0.f};

  #pragma unroll
  for (int kc=0; kc<2; ++kc){
    const int aidx = (p*64 + kc*32 + kg*8) ^ ((p&7)<<3);
    u16x8 au = *(const u16x8*)(&hbuf[wave][aidx]);
    bf16x8 ab = __builtin_bit_cast(bf16x8, au);
    #pragma unroll
    for (int tt=0; tt<4; ++tt){
      const int col = (lane&15) + (tt<<4);
      u16x8 bu = *(const u16x8*)(w2s + (col<<6) + ((((kc<<2)+kg) ^ (col&7))<<3));
      acc2[tt] = __builtin_amdgcn_mfma_f32_16x16x32_bf16(
          ab, __builtin_bit_cast(bf16x8, bu), acc2[tt], 0,0,0);
    }
  }
  // overwrite h1 with h2 in place: all h1 reads (above) precede these writes
  // in this wave's program order; LDS ops within a wave execute in order.
  #pragma unroll
  for (int tt=0; tt<4; ++tt){
    const int col = (lane&15) + (tt<<4);
    const float bias = b2[col];
    #pragma unroll
    for (int r=0; r<4; ++r){
      const int row = (kg<<2) + r;
      float v = acc2[tt][r] + bias;
      v = v > 0.f ? v : 0.f;
      hbuf[wave][(row*64 + col) ^ ((row&7)<<3)] = f2bf(v);
    }
  }

  // ---- layer 3: [16 x 64] @ [64 x 3] + sigmoid ----
  if (lane < 48){
    const int pp = lane / 3, c = lane % 3;
    float sum = b3[c];
    #pragma unroll
    for (int o=0; o<64; ++o){
      sum += bf2f(hbuf[wave][(pp*64+o) ^ ((pp&7)<<3)]) * W3[o*3+c];
    }
    const int gpp = (blockIdx.x << 7) + (wave << 4) + pp;
    color[(size_t)gpp*3 + c] = 1.f/(1.f+__expf(-sum));
  }
}

extern "C" void kernel_launch(void* const* d_in, const int* in_sizes, int n_in,
                              void* d_out, int out_size, void* d_ws, size_t ws_size,
                              hipStream_t stream){
  const float* xyz  = (const float*)d_in[0];
  const float* fg   = (const float*)d_in[1];
  const float* dens = (const float*)d_in[2];
  const float* W1   = (const float*)d_in[3];
  const float* b1   = (const float*)d_in[4];
  const float* W2   = (const float*)d_in[5];
  const float* b2   = (const float*)d_in[6];
  const float* W3   = (const float*)d_in[7];
  const float* b3   = (const float*)d_in[8];
  float* out = (float*)d_out;

  u16* W1T = (u16*)d_ws;            // 64*512*2 = 64 KiB
  u16* W2T = W1T + 64*512;          // 64*64*2  =  8 KiB

  hipLaunchKernelGGL(prep_weights, dim3(64), dim3(256), 0, stream, W1, W2, W1T, W2T);
  hipLaunchKernelGGL(density_sigmoid, dim3(DENS_N/1024), dim3(256), 0, stream,
                     (const float4*)dens, (float4*)out);
  hipLaunchKernelGGL(fused_mlp, dim3(NPTS/128), dim3(512), 0, stream,
                     xyz, fg, W1T, W2T, b1, b2, W3, b3, out + DENS_N);
}

// Round 8
// 131.237 us; speedup vs baseline: 1.3006x; 1.1816x over previous
//
#include <hip/hip_runtime.h>
#include <hip/hip_bf16.h>
#include <cstdint>

#define HASH_SIZE (1u<<19)
#define NPTS 262144
#define DENS_N 2097152

typedef unsigned short u16;
typedef u16 u16x8 __attribute__((ext_vector_type(8)));
typedef __bf16 bf16x8 __attribute__((ext_vector_type(8)));
typedef float f32x4 __attribute__((ext_vector_type(4)));

__device__ __forceinline__ u16 f2bf(float f){
  uint32_t u = __builtin_bit_cast(uint32_t, f);
  u += 0x7fffu + ((u>>16)&1u);       // RNE; inputs are finite
  return (u16)(u>>16);
}
__device__ __forceinline__ float bf2f(u16 s){
  uint32_t u = ((uint32_t)s)<<16;
  return __builtin_bit_cast(float, u);
}

// W1 [512][64] f32 -> W1T [64][512] bf16 ; W2 [64][64] f32 -> W2T [64][64] bf16
__global__ void prep_weights(const float* __restrict__ W1, const float* __restrict__ W2,
                             u16* __restrict__ W1T, u16* __restrict__ W2T){
  int t = blockIdx.x*blockDim.x + threadIdx.x;
  int stride = gridDim.x*blockDim.x;
  for (int i=t; i<64*512; i+=stride){ int o=i>>9, k=i&511; W1T[i] = f2bf(W1[k*64+o]); }
  for (int i=t; i<64*64;  i+=stride){ int o=i>>6, k=i&63;  W2T[i] = f2bf(W2[k*64+o]); }
}

__global__ void density_sigmoid(const float4* __restrict__ in, float4* __restrict__ out){
  int i = blockIdx.x*blockDim.x + threadIdx.x;   // exactly 524288 threads
  float4 v = in[i];
  v.x = 1.f/(1.f+__expf(-v.x));
  v.y = 1.f/(1.f+__expf(-v.y));
  v.z = 1.f/(1.f+__expf(-v.z));
  v.w = 1.f/(1.f+__expf(-v.w));
  out[i] = v;
}

// 512 threads = 8 independent waves, 16 points each (128 pts/block).
// W1T+W2T staged in LDS; only global VMEM in the hot path is the 32 gather
// loads per wave, issued with sc0 (device scope = L1 BYPASS, L2/L3 allocate
// normally). The gather stream has zero L1 reuse; bypassing L1 frees its
// MSHR slots — the hypothesized per-CU concurrency limit.
__global__ void __launch_bounds__(512) fused_mlp(
    const float* __restrict__ xyz, const float* __restrict__ fg,
    const u16* __restrict__ W1T, const u16* __restrict__ W2T,
    const float* __restrict__ b1, const float* __restrict__ b2,
    const float* __restrict__ W3, const float* __restrict__ b3,
    float* __restrict__ color)
{
  __shared__ u16 w1s[64*512];      // 64 KiB, granule-swizzled
  __shared__ u16 w2s[64*64];       // 8 KiB, granule-swizzled
  __shared__ u16 hbuf[8][16*64];   // 16 KiB; h1 then h2 in place (same-wave)

  const int t = threadIdx.x;
  const int wave = t >> 6;
  const int lane = t & 63;
  const int p  = lane & 15;            // point within this wave's 16-point tile
  const int kg = lane >> 4;            // k-subgroup 0..3
  const int gp = (blockIdx.x << 7) + (wave << 4) + p;   // global point id

  // ---- issue gather loads FIRST (misses start early; 32 in flight/wave) ----
  const float x = xyz[gp*3+0];
  const float y = xyz[gp*3+1];
  const float z = xyz[gp*3+2];
  f32x4 a0[16], a1[16];
  #pragma unroll
  for (int s=0; s<16; ++s){
    const float resf = (float)(16 << s);
    uint32_t ix = (uint32_t)(x*resf);
    uint32_t iy = (uint32_t)(y*resf);
    uint32_t iz = (uint32_t)(z*resf);
    uint32_t h = (ix ^ (iy*2654435761u) ^ (iz*805459861u)) & (HASH_SIZE-1u);
    const float* ap = fg + (size_t)((((uint32_t)s<<19) | h) * 32u) + (kg<<3);
    // L1-bypass (sc0), L2/L3 allocate. Compiler doesn't track these loads:
    // an explicit vmcnt(0) fence below guards all consumers.
    asm volatile("global_load_dwordx4 %0, %2, off sc0\n\t"
                 "global_load_dwordx4 %1, %2, off offset:16 sc0"
                 : "=v"(a0[s]), "=v"(a1[s]) : "v"(ap));
  }

  // ---- stage W1T/W2T into LDS (cooperative, swizzled granules of 16 B) ----
  // w1s: granule (col, g) g=0..63 stored at col*512 + (g ^ (col&7))*8 (u16 units)
  #pragma unroll
  for (int i=0; i<8; ++i){
    int g = t + (i<<9);                 // 512 threads x 8 = 4096 granules
    int col = g >> 6, gr = g & 63;
    u16x8 v = *(const u16x8*)(W1T + (g<<3));
    *(u16x8*)(w1s + (col<<9) + (((gr) ^ (col&7))<<3)) = v;
  }
  {
    int g = t;                           // 512 granules
    int col = g >> 3, gr = g & 7;
    u16x8 v = *(const u16x8*)(W2T + (g<<3));
    *(u16x8*)(w2s + (col<<6) + (((gr) ^ (col&7))<<3)) = v;
  }
  __syncthreads();

  // all asm gather loads complete before any consumer (rule #18: waitcnt asm
  // alone doesn't fence register-only consumers -> sched_barrier required)
  asm volatile("s_waitcnt vmcnt(0)" ::: "memory");
  __builtin_amdgcn_sched_barrier(0);

  // ---- GEMM1: features @ W1 -> h1 [16 x 64] ----
  f32x4 acc[4];
  #pragma unroll
  for (int tt=0; tt<4; ++tt) acc[tt] = (f32x4){0.f,0.f,0.f,0.f};

  #pragma unroll
  for (int s=0; s<16; ++s){
    bf16x8 ab = { (__bf16)a0[s][0], (__bf16)a0[s][1], (__bf16)a0[s][2], (__bf16)a0[s][3],
                  (__bf16)a1[s][0], (__bf16)a1[s][1], (__bf16)a1[s][2], (__bf16)a1[s][3] };
    #pragma unroll
    for (int tt=0; tt<4; ++tt){
      const int col = (lane&15) + (tt<<4);
      u16x8 bu = *(const u16x8*)(w1s + (col<<9) + ((((s<<2)+kg) ^ (col&7))<<3));
      acc[tt] = __builtin_amdgcn_mfma_f32_16x16x32_bf16(
          ab, __builtin_bit_cast(bf16x8, bu), acc[tt], 0,0,0);
    }
  }
  #pragma unroll
  for (int tt=0; tt<4; ++tt){
    const int col = (lane&15) + (tt<<4);
    const float bias = b1[col];
    #pragma unroll
    for (int r=0; r<4; ++r){
      const int row = (kg<<2) + r;        // C row = point within tile
      float v = acc[tt][r] + bias;
      v = v > 0.f ? v : 0.f;
      hbuf[wave][(row*64 + col) ^ ((row&7)<<3)] = f2bf(v);  // XOR-swizzled
    }
  }

  // ---- GEMM2: h1 @ W2 -> h2 [16 x 64] ---- (same-wave LDS deps; no barrier)
  f32x4 acc2[4];
  #pragma unroll
  for (int tt=0; tt<4; ++tt) acc2[tt] = (f32x4){0.f,0.f,0.f,0.f};

  #pragma unroll
  for (int kc=0; kc<2; ++kc){
    const int aidx = (p*64 + kc*32 + kg*8) ^ ((p&7)<<3);
    u16x8 au = *(const u16x8*)(&hbuf[wave][aidx]);
    bf16x8 ab = __builtin_bit_cast(bf16x8, au);
    #pragma unroll
    for (int tt=0; tt<4; ++tt){
      const int col = (lane&15) + (tt<<4);
      u16x8 bu = *(const u16x8*)(w2s + (col<<6) + ((((kc<<2)+kg) ^ (col&7))<<3));
      acc2[tt] = __builtin_amdgcn_mfma_f32_16x16x32_bf16(
          ab, __builtin_bit_cast(bf16x8, bu), acc2[tt], 0,0,0);
    }
  }
  // overwrite h1 with h2 in place: all h1 reads (above) precede these writes
  // in this wave's program order; LDS ops within a wave execute in order.
  #pragma unroll
  for (int tt=0; tt<4; ++tt){
    const int col = (lane&15) + (tt<<4);
    const float bias = b2[col];
    #pragma unroll
    for (int r=0; r<4; ++r){
      const int row = (kg<<2) + r;
      float v = acc2[tt][r] + bias;
      v = v > 0.f ? v : 0.f;
      hbuf[wave][(row*64 + col) ^ ((row&7)<<3)] = f2bf(v);
    }
  }

  // ---- layer 3: [16 x 64] @ [64 x 3] + sigmoid ----
  if (lane < 48){
    const int pp = lane / 3, c = lane % 3;
    float sum = b3[c];
    #pragma unroll
    for (int o=0; o<64; ++o){
      sum += bf2f(hbuf[wave][(pp*64+o) ^ ((pp&7)<<3)]) * W3[o*3+c];
    }
    const int gpp = (blockIdx.x << 7) + (wave << 4) + pp;
    color[(size_t)gpp*3 + c] = 1.f/(1.f+__expf(-sum));
  }
}

extern "C" void kernel_launch(void* const* d_in, const int* in_sizes, int n_in,
                              void* d_out, int out_size, void* d_ws, size_t ws_size,
                              hipStream_t stream){
  const float* xyz  = (const float*)d_in[0];
  const float* fg   = (const float*)d_in[1];
  const float* dens = (const float*)d_in[2];
  const float* W1   = (const float*)d_in[3];
  const float* b1   = (const float*)d_in[4];
  const float* W2   = (const float*)d_in[5];
  const float* b2   = (const float*)d_in[6];
  const float* W3   = (const float*)d_in[7];
  const float* b3   = (const float*)d_in[8];
  float* out = (float*)d_out;

  u16* W1T = (u16*)d_ws;            // 64*512*2 = 64 KiB
  u16* W2T = W1T + 64*512;          // 64*64*2  =  8 KiB

  hipLaunchKernelGGL(prep_weights, dim3(64), dim3(256), 0, stream, W1, W2, W1T, W2T);
  hipLaunchKernelGGL(density_sigmoid, dim3(DENS_N/1024), dim3(256), 0, stream,
                     (const float4*)dens, (float4*)out);
  hipLaunchKernelGGL(fused_mlp, dim3(NPTS/128), dim3(512), 0, stream,
                     xyz, fg, W1T, W2T, b1, b2, W3, b3, out + DENS_N);
}

// Round 9
// 129.615 us; speedup vs baseline: 1.3169x; 1.0125x over previous
//
#include <hip/hip_runtime.h>
#include <hip/hip_bf16.h>
#include <cstdint>

#define HASH_SIZE (1u<<19)
#define NPTS 262144
#define DENS_N 2097152

typedef unsigned short u16;
typedef u16 u16x8 __attribute__((ext_vector_type(8)));
typedef __bf16 bf16x8 __attribute__((ext_vector_type(8)));
typedef float f32x4 __attribute__((ext_vector_type(4)));

__device__ __forceinline__ u16 f2bf(float f){
  uint32_t u = __builtin_bit_cast(uint32_t, f);
  u += 0x7fffu + ((u>>16)&1u);       // RNE; inputs are finite
  return (u16)(u>>16);
}
__device__ __forceinline__ float bf2f(u16 s){
  uint32_t u = ((uint32_t)s)<<16;
  return __builtin_bit_cast(float, u);
}

// W1 [512][64] f32 -> W1T [64][512] bf16 with the K-dim PERMUTED inside each
// 32-wide level chunk so each gather instruction touches ONE contiguous 64B
// sector per row:  k_mfma = kg*8+j  holds  k_orig = (j>>2)*16 + kg*4 + (j&3).
// A-fragment uses the same permutation -> dot product unchanged.
// W2 [64][64] f32 -> W2T [64][64] bf16 (unpermuted).
__global__ void prep_weights(const float* __restrict__ W1, const float* __restrict__ W2,
                             u16* __restrict__ W1T, u16* __restrict__ W2T){
  int t = blockIdx.x*blockDim.x + threadIdx.x;
  int stride = gridDim.x*blockDim.x;
  for (int i=t; i<64*512; i+=stride){
    int o = i>>9, k = i&511;
    int s = k>>5, km = k&31, kg = km>>3, j = km&7;
    int k_orig = ((j>>2)<<4) + (kg<<2) + (j&3);
    W1T[i] = f2bf(W1[((s<<5) + k_orig)*64 + o]);
  }
  for (int i=t; i<64*64;  i+=stride){ int o=i>>6, k=i&63;  W2T[i] = f2bf(W2[k*64+o]); }
}

__global__ void density_sigmoid(const float4* __restrict__ in, float4* __restrict__ out){
  int i = blockIdx.x*blockDim.x + threadIdx.x;   // exactly 524288 threads
  float4 v = in[i];
  v.x = 1.f/(1.f+__expf(-v.x));
  v.y = 1.f/(1.f+__expf(-v.y));
  v.z = 1.f/(1.f+__expf(-v.z));
  v.w = 1.f/(1.f+__expf(-v.w));
  out[i] = v;
}

// 512 threads = 8 independent waves, 16 points each (128 pts/block).
// W1T+W2T staged in LDS (R5 structure). Gather lane layout is K-permuted so
// each dwordx4 instruction's per-row footprint is one contiguous 64B sector:
// a0 lanes cover bytes [0,64), a1 lanes [64,128) -> 2 sector-requests per row
// instead of 4, halving the transaction count through TA/L1/L2/fabric.
__global__ void __launch_bounds__(512) fused_mlp(
    const float* __restrict__ xyz, const float* __restrict__ fg,
    const u16* __restrict__ W1T, const u16* __restrict__ W2T,
    const float* __restrict__ b1, const float* __restrict__ b2,
    const float* __restrict__ W3, const float* __restrict__ b3,
    float* __restrict__ color)
{
  __shared__ u16 w1s[64*512];      // 64 KiB, granule-swizzled
  __shared__ u16 w2s[64*64];       // 8 KiB, granule-swizzled
  __shared__ u16 hbuf[8][16*64];   // 16 KiB; h1 then h2 in place (same-wave)

  const int t = threadIdx.x;
  const int wave = t >> 6;
  const int lane = t & 63;
  const int p  = lane & 15;            // point within this wave's 16-point tile
  const int kg = lane >> 4;            // k-subgroup 0..3
  const int gp = (blockIdx.x << 7) + (wave << 4) + p;   // global point id

  // ---- issue gather loads FIRST (misses start early; 32 in flight/wave) ----
  const float x = xyz[gp*3+0];
  const float y = xyz[gp*3+1];
  const float z = xyz[gp*3+2];
  f32x4 a0[16], a1[16];
  #pragma unroll
  for (int s=0; s<16; ++s){
    const float resf = (float)(16 << s);
    uint32_t ix = (uint32_t)(x*resf);
    uint32_t iy = (uint32_t)(y*resf);
    uint32_t iz = (uint32_t)(z*resf);
    uint32_t h = (ix ^ (iy*2654435761u) ^ (iz*805459861u)) & (HASH_SIZE-1u);
    const float* ap = fg + (size_t)((((uint32_t)s<<19) | h) * 32u);
    a0[s] = *(const f32x4*)(ap + (kg<<2));          // bytes [kg*16, kg*16+16)
    a1[s] = *(const f32x4*)(ap + 16 + (kg<<2));     // bytes [64+kg*16, ...)
  }

  // ---- stage W1T/W2T into LDS (cooperative, swizzled granules of 16 B) ----
  // w1s: granule (col, g) g=0..63 stored at col*512 + (g ^ (col&7))*8 (u16 units)
  #pragma unroll
  for (int i=0; i<8; ++i){
    int g = t + (i<<9);                 // 512 threads x 8 = 4096 granules
    int col = g >> 6, gr = g & 63;
    u16x8 v = *(const u16x8*)(W1T + (g<<3));
    *(u16x8*)(w1s + (col<<9) + (((gr) ^ (col&7))<<3)) = v;
  }
  {
    int g = t;                           // 512 granules
    int col = g >> 3, gr = g & 7;
    u16x8 v = *(const u16x8*)(W2T + (g<<3));
    *(u16x8*)(w2s + (col<<6) + (((gr) ^ (col&7))<<3)) = v;
  }
  __syncthreads();

  // ---- GEMM1: features @ W1 -> h1 [16 x 64] ----
  f32x4 acc[4];
  #pragma unroll
  for (int tt=0; tt<4; ++tt) acc[tt] = (f32x4){0.f,0.f,0.f,0.f};

  #pragma unroll
  for (int s=0; s<16; ++s){
    bf16x8 ab = { (__bf16)a0[s][0], (__bf16)a0[s][1], (__bf16)a0[s][2], (__bf16)a0[s][3],
                  (__bf16)a1[s][0], (__bf16)a1[s][1], (__bf16)a1[s][2], (__bf16)a1[s][3] };
    #pragma unroll
    for (int tt=0; tt<4; ++tt){
      const int col = (lane&15) + (tt<<4);
      u16x8 bu = *(const u16x8*)(w1s + (col<<9) + ((((s<<2)+kg) ^ (col&7))<<3));
      acc[tt] = __builtin_amdgcn_mfma_f32_16x16x32_bf16(
          ab, __builtin_bit_cast(bf16x8, bu), acc[tt], 0,0,0);
    }
  }
  #pragma unroll
  for (int tt=0; tt<4; ++tt){
    const int col = (lane&15) + (tt<<4);
    const float bias = b1[col];
    #pragma unroll
    for (int r=0; r<4; ++r){
      const int row = (kg<<2) + r;        // C row = point within tile
      float v = acc[tt][r] + bias;
      v = v > 0.f ? v : 0.f;
      hbuf[wave][(row*64 + col) ^ ((row&7)<<3)] = f2bf(v);  // XOR-swizzled
    }
  }

  // ---- GEMM2: h1 @ W2 -> h2 [16 x 64] ---- (same-wave LDS deps; no barrier)
  f32x4 acc2[4];
  #pragma unroll
  for (int tt=0; tt<4; ++tt) acc2[tt] = (f32x4){0.f,0.f,0.f,0.f};

  #pragma unroll
  for (int kc=0; kc<2; ++kc){
    const int aidx = (p*64 + kc*32 + kg*8) ^ ((p&7)<<3);
    u16x8 au = *(const u16x8*)(&hbuf[wave][aidx]);
    bf16x8 ab = __builtin_bit_cast(bf16x8, au);
    #pragma unroll
    for (int tt=0; tt<4; ++tt){
      const int col = (lane&15) + (tt<<4);
      u16x8 bu = *(const u16x8*)(w2s + (col<<6) + ((((kc<<2)+kg) ^ (col&7))<<3));
      acc2[tt] = __builtin_amdgcn_mfma_f32_16x16x32_bf16(
          ab, __builtin_bit_cast(bf16x8, bu), acc2[tt], 0,0,0);
    }
  }
  // overwrite h1 with h2 in place: all h1 reads (above) precede these writes
  // in this wave's program order; LDS ops within a wave execute in order.
  #pragma unroll
  for (int tt=0; tt<4; ++tt){
    const int col = (lane&15) + (tt<<4);
    const float bias = b2[col];
    #pragma unroll
    for (int r=0; r<4; ++r){
      const int row = (kg<<2) + r;
      float v = acc2[tt][r] + bias;
      v = v > 0.f ? v : 0.f;
      hbuf[wave][(row*64 + col) ^ ((row&7)<<3)] = f2bf(v);
    }
  }

  // ---- layer 3: [16 x 64] @ [64 x 3] + sigmoid ----
  if (lane < 48){
    const int pp = lane / 3, c = lane % 3;
    float sum = b3[c];
    #pragma unroll
    for (int o=0; o<64; ++o){
      sum += bf2f(hbuf[wave][(pp*64+o) ^ ((pp&7)<<3)]) * W3[o*3+c];
    }
    const int gpp = (blockIdx.x << 7) + (wave << 4) + pp;
    color[(size_t)gpp*3 + c] = 1.f/(1.f+__expf(-sum));
  }
}

extern "C" void kernel_launch(void* const* d_in, const int* in_sizes, int n_in,
                              void* d_out, int out_size, void* d_ws, size_t ws_size,
                              hipStream_t stream){
  const float* xyz  = (const float*)d_in[0];
  const float* fg   = (const float*)d_in[1];
  const float* dens = (const float*)d_in[2];
  const float* W1   = (const float*)d_in[3];
  const float* b1   = (const float*)d_in[4];
  const float* W2   = (const float*)d_in[5];
  const float* b2   = (const float*)d_in[6];
  const float* W3   = (const float*)d_in[7];
  const float* b3   = (const float*)d_in[8];
  float* out = (float*)d_out;

  u16* W1T = (u16*)d_ws;            // 64*512*2 = 64 KiB
  u16* W2T = W1T + 64*512;          // 64*64*2  =  8 KiB

  hipLaunchKernelGGL(prep_weights, dim3(64), dim3(256), 0, stream, W1, W2, W1T, W2T);
  hipLaunchKernelGGL(density_sigmoid, dim3(DENS_N/1024), dim3(256), 0, stream,
                     (const float4*)dens, (float4*)out);
  hipLaunchKernelGGL(fused_mlp, dim3(NPTS/128), dim3(512), 0, stream,
                     xyz, fg, W1T, W2T, b1, b2, W3, b3, out + DENS_N);
}